// Round 12
// baseline (202.344 us; speedup 1.0000x reference)
//
#include <hip/hip_runtime.h>
#include <stdint.h>

typedef __attribute__((ext_vector_type(8))) short bf16x8;
typedef __attribute__((ext_vector_type(4))) float f32x4;
typedef __attribute__((ext_vector_type(16))) float f32x16;
typedef __attribute__((ext_vector_type(8))) unsigned short ushort8;
typedef __attribute__((ext_vector_type(4))) unsigned short ushort4v;

#define MFMA16(a, b, c) __builtin_amdgcn_mfma_f32_16x16x32_bf16((a), (b), (c), 0, 0, 0)
#define MFMA32(a, b, c) __builtin_amdgcn_mfma_f32_32x32x16_bf16((a), (b), (c), 0, 0, 0)

// B=8, S=1024, D=1024, H=16, DK=64
#define SLEN 1024
#define NHEAD 16
#define HDIM 64
#define DMODEL 1024
#define NROWS 8192  // B*S
#define LOG2E 1.44269504088896340736f

__device__ __forceinline__ unsigned short f2bf(float f) {
  unsigned int u = __float_as_uint(f);
  u += 0x7FFFu + ((u >> 16) & 1u);   // RNE
  return (unsigned short)(u >> 16);
}

__device__ __forceinline__ float fast_exp2(float x) {
#if __has_builtin(__builtin_amdgcn_exp2f)
  return __builtin_amdgcn_exp2f(x);
#else
  float r; asm("v_exp_f32 %0, %1" : "=v"(r) : "v"(x)); return r;
#endif
}

__device__ __forceinline__ unsigned int cvt_pk_bf16(float lo, float hi) {
  unsigned int r;
  asm("v_cvt_pk_bf16_f32 %0, %1, %2" : "=v"(r) : "v"(lo), "v"(hi));
  return r;
}

// async global->LDS, 16B per lane; LDS dest = wave-uniform base + lane*16 (HW).
__device__ __forceinline__ void gload_lds16(const void* g, void* l) {
  __builtin_amdgcn_global_load_lds(
      (const __attribute__((address_space(1))) void*)g,
      (__attribute__((address_space(3))) void*)l, 16, 0, 0);
}

// ---------------- convert hidden_states f32 -> bf16 ----------------
__global__ __launch_bounds__(256) void k_convert_x(const float* __restrict__ x,
                                                   unsigned short* __restrict__ xb, int n) {
  int i = blockIdx.x * 256 + threadIdx.x;
  int idx = i * 8;
  if (idx >= n) return;
  float4 a = *(const float4*)(x + idx);
  float4 b = *(const float4*)(x + idx + 4);
  ushort8 o;
  o[0] = f2bf(a.x); o[1] = f2bf(a.y); o[2] = f2bf(a.z); o[3] = f2bf(a.w);
  o[4] = f2bf(b.x); o[5] = f2bf(b.y); o[6] = f2bf(b.z); o[7] = f2bf(b.w);
  *(ushort8*)(xb + idx) = o;
}

// ---------------- transpose + convert weights: W[K][N] f32 -> Wt[N][K] bf16 ----------------
__global__ __launch_bounds__(256) void k_transpose_w(
    const float* __restrict__ w0, const float* __restrict__ w1,
    const float* __restrict__ w2, const float* __restrict__ w3,
    unsigned short* __restrict__ o0, unsigned short* __restrict__ o1,
    unsigned short* __restrict__ o2, unsigned short* __restrict__ o3) {
  int z = blockIdx.z;
  const float* w = (z == 0) ? w0 : (z == 1) ? w1 : (z == 2) ? w2 : w3;
  unsigned short* o = (z == 0) ? o0 : (z == 1) ? o1 : (z == 2) ? o2 : o3;
  __shared__ unsigned short tile[32][33];
  int bx = blockIdx.x & 31, by = blockIdx.x >> 5;
  int tid = threadIdx.x;
#pragma unroll
  for (int p = 0; p < 4; ++p) {
    int idx = tid + p * 256;
    int r = idx >> 5, c = idx & 31;
    tile[r][c] = f2bf(w[(size_t)(by * 32 + r) * DMODEL + bx * 32 + c]);
  }
  __syncthreads();
#pragma unroll
  for (int p = 0; p < 4; ++p) {
    int idx = tid + p * 256;
    int r = idx >> 5, c = idx & 31;
    o[(size_t)(bx * 32 + r) * DMODEL + by * 32 + c] = tile[c][r];
  }
}

// ---------------- relative-position bias table: bt[h][rel+1023] * log2e, rel=k-q ----------------
__global__ __launch_bounds__(256) void k_bias_table(const float* __restrict__ rel_bias,
                                                    float* __restrict__ bt) {
  int i = blockIdx.x * 256 + threadIdx.x;
  if (i >= NHEAD * 2047) return;
  int h = i / 2047, rdx = i % 2047;
  int rel = rdx - 1023;
  int rb = (rel > 0) ? 16 : 0;
  int rp = (rel < 0) ? -rel : rel;
  int bucket;
  if (rp < 8) {
    bucket = rb + rp;
  } else {
    // large = 8 + floor(2*log2(rp)) - 6, capped at 15. Integer-exact via clz+square.
    int large;
    if (rp >= 91) {
      large = 15;
    } else {
      int nb = 31 - __clz(rp);
      long long sq = (long long)rp * rp;
      int f2 = 2 * nb + ((sq >= (1LL << (2 * nb + 1))) ? 1 : 0);
      large = 8 + (f2 - 6);
      if (large > 15) large = 15;
    }
    bucket = rb + large;
  }
  bt[h * 2048 + rdx] = rel_bias[bucket * 16 + h] * LOG2E;  // log2e domain
}

// ---------------- 2-phase GEMM core, BK=64, XOR-swizzled LDS (R10-verified) ----------------
__device__ __forceinline__ void gemm_tile_lds(const unsigned short* __restrict__ A,
                                              const unsigned short* __restrict__ Bt,
                                              int K, int tm, int tn,
                                              unsigned short* As, unsigned short* Bs,
                                              f32x4 acc[4][4]) {
  const int tid = threadIdx.x;
  const int lane = tid & 63;
  const int w = tid >> 6;
  const int wr = w >> 1, wc = w & 1;
  const int g = lane >> 4, t = lane & 15;
  const int NKT = K >> 6;   // BK=64

  auto stageT = [&](int bufo, int ko) {
#pragma unroll
    for (int j = 0; j < 4; ++j) {
      const int r = w * 32 + j * 8 + (lane >> 3);
      const int lc = (lane & 7) ^ (r & 7);
      gload_lds16(A + (size_t)(tm + r) * K + ko + lc * 8, As + bufo + (w * 4 + j) * 512);
      gload_lds16(Bt + (size_t)(tn + r) * K + ko + lc * 8, Bs + bufo + (w * 4 + j) * 512);
    }
  };

  f32x4 z = {0.f, 0.f, 0.f, 0.f};
#pragma unroll
  for (int mi = 0; mi < 4; ++mi)
#pragma unroll
    for (int ni = 0; ni < 4; ++ni) acc[mi][ni] = z;

  stageT(0, 0);
  __syncthreads();

#pragma unroll 1
  for (int kt = 0; kt < NKT; ++kt) {
    const int cur = (kt & 1) * 8192;
    if (kt + 1 < NKT) stageT(cur ^ 8192, (kt + 1) * 64);

    bf16x8 af[2][4], bfr[2][4];
#pragma unroll
    for (int kk = 0; kk < 2; ++kk)
#pragma unroll
      for (int mi = 0; mi < 4; ++mi) {
        const int ra = wr * 64 + mi * 16 + t;
        const int pa = ((kk << 2) | g) ^ (ra & 7);
        af[kk][mi] = *(const bf16x8*)&As[cur + ra * 64 + pa * 8];
      }
#pragma unroll
    for (int kk = 0; kk < 2; ++kk)
#pragma unroll
      for (int ni = 0; ni < 4; ++ni) {
        const int rb = wc * 64 + ni * 16 + t;
        const int pb = ((kk << 2) | g) ^ (rb & 7);
        bfr[kk][ni] = *(const bf16x8*)&Bs[cur + rb * 64 + pb * 8];
      }
#pragma unroll
    for (int kk = 0; kk < 2; ++kk)
#pragma unroll
      for (int mi = 0; mi < 4; ++mi)
#pragma unroll
        for (int ni = 0; ni < 4; ++ni)
          acc[mi][ni] = MFMA16(af[kk][mi], bfr[kk][ni], acc[mi][ni]);

    __syncthreads();
  }
}

// ---------------- QKV projection ----------------
__global__ __launch_bounds__(256) void k_gemm_qkv(
    const unsigned short* __restrict__ Xb,
    const unsigned short* __restrict__ Wqt, const unsigned short* __restrict__ Wkt,
    const unsigned short* __restrict__ Wvt,
    unsigned short* __restrict__ Qb, unsigned short* __restrict__ Kb,
    unsigned short* __restrict__ Vt) {
  __shared__ alignas(16) unsigned short As[2 * 128 * 64];
  __shared__ alignas(16) unsigned short Bs[2 * 128 * 64];
  int z = blockIdx.z;
  const unsigned short* Bt = (z == 0) ? Wqt : (z == 1) ? Wkt : Wvt;
  const int wid = (blockIdx.x & 7) * 64 + (blockIdx.x >> 3);
  int tm = (wid >> 3) * 128, tn = (wid & 7) * 128;
  f32x4 acc[4][4];
  gemm_tile_lds(Xb, Bt, DMODEL, tm, tn, As, Bs, acc);

  const int lane = threadIdx.x & 63, w = threadIdx.x >> 6;
  const int wr = w >> 1, wc = w & 1, g = lane >> 4, t = lane & 15;
  if (z < 2) {
    unsigned short* O = (z == 0) ? Qb : Kb;
#pragma unroll
    for (int mi = 0; mi < 4; ++mi)
#pragma unroll
      for (int ni = 0; ni < 4; ++ni)
#pragma unroll
        for (int r = 0; r < 4; ++r) {
          int m = tm + wr * 64 + mi * 16 + g * 4 + r;
          int n = tn + wc * 64 + ni * 16 + t;
          int b = m >> 10, s = m & 1023, h = n >> 6, d = n & 63;
          O[((size_t)((b * 16 + h) * 1024 + s)) * 64 + d] = f2bf(acc[mi][ni][r]);
        }
  } else {
#pragma unroll
    for (int mi = 0; mi < 4; ++mi)
#pragma unroll
      for (int ni = 0; ni < 4; ++ni) {
        int m0 = tm + wr * 64 + mi * 16 + g * 4;
        int n = tn + wc * 64 + ni * 16 + t;
        int b = m0 >> 10, s0 = m0 & 1023, h = n >> 6, d = n & 63;
        ushort4v pk;
#pragma unroll
        for (int r = 0; r < 4; ++r) pk[r] = f2bf(acc[mi][ni][r]);
        *(ushort4v*)&Vt[((size_t)((b * 16 + h) * 64 + d) * 1024) + s0] = pk;
      }
  }
}

// ---------------- flash attention ----------------
// grid 512 (XCD-swizzled); block 256 = 4 waves; wave = 64 q-rows as two sequential
// 32-row groups (A/B) sharing one K/V LDS-fragment read. Per-q-row op sequence is
// op-for-op identical to R10 (bit-identical output). Cross-lane via shfl_xor (verified).
__global__ __launch_bounds__(256) void k_attn(
    const unsigned short* __restrict__ Qb, const unsigned short* __restrict__ Kb,
    const unsigned short* __restrict__ Vt, const float* __restrict__ bt,
    unsigned short* __restrict__ ctx) {
  __shared__ alignas(16) unsigned short Ks[2][64 * 64];  // [key][d] swizzled, 8KB each
  __shared__ alignas(16) unsigned short Vs[2][64 * 64];  // [d][key] swizzled, 8KB each
  __shared__ alignas(16) float Lb[376];                  // bias, rel in [-186,189], log2e domain
  __shared__ float sred[4][32];

  const int wid = ((blockIdx.x & 7) << 6) | (blockIdx.x >> 3);  // XCD-local head grouping
  const int bh = wid >> 2, qb = wid & 3;
  const int h = bh & 15, b = bh >> 4;
  const int tid = threadIdx.x;
  const int lane = tid & 63, w = tid >> 6;   // w in 0..3
  const int ql = lane & 31, hi = lane >> 5;
  const int q0 = qb * 256 + w * 64;          // wave owns rows [q0, q0+64)

  for (int i = tid; i < 376; i += 256) Lb[i] = bt[(size_t)h * 2048 + 837 + i];  // 837 = 1023-186

  const unsigned short* Qp = Qb + (size_t)bh * SLEN * 64;
  const unsigned short* Kp = Kb + (size_t)bh * SLEN * 64;
  const unsigned short* Vp = Vt + (size_t)bh * 64 * SLEN;

  // Q as B-operand for both groups: col=lane&31=q, d contiguous 8 at hi*8 per 16-chunk
  bf16x8 bq[2][4];
#pragma unroll
  for (int G = 0; G < 2; ++G)
#pragma unroll
    for (int c = 0; c < 4; ++c)
      bq[G][c] = *(const bf16x8*)(Qp + (size_t)(q0 + G * 32 + ql) * 64 + c * 16 + hi * 8);

  const f32x16 z16 = {0.f,0.f,0.f,0.f,0.f,0.f,0.f,0.f,0.f,0.f,0.f,0.f,0.f,0.f,0.f,0.f};
  f32x16 o[2][2];
  o[0][0] = z16; o[0][1] = z16; o[1][0] = z16; o[1][1] = z16;
  float m[2] = {-INFINITY, -INFINITY}, l[2] = {0.f, 0.f};

  // stage tile: 8KB K + 8KB V; wave w covers bytes [w*2048, w*2048+2048) of each (R7-verified).
  auto stage = [&](int buf, int kbase) {
#pragma unroll
    for (int j = 0; j < 2; ++j) {
      int lb = w * 2048 + j * 1024 + lane * 16;
      int row = lb >> 7;
      int lc = ((lb >> 4) & 7) ^ (row & 7);
      gload_lds16(Kp + (size_t)(kbase + row) * 64 + lc * 8, &Ks[buf][w * 1024 + j * 512]);
      gload_lds16(Vp + (size_t)row * SLEN + kbase + lc * 8, &Vs[buf][w * 1024 + j * 512]);
    }
  };

  stage(0, 0);
  __syncthreads();
  const float cpos = Lb[186 + 91], cneg = Lb[186 - 91];

  int cur = 0;
#pragma unroll 1
  for (int kt = 0; kt < 16; ++kt) {
    const int kbase = kt * 64;
    if (kt != 15) stage(cur ^ 1, kbase + 64);

    const char* Kc = (const char*)Ks[cur];
    const char* Vc = (const char*)Vs[cur];

#pragma unroll
    for (int hh = 0; hh < 2; ++hh) {
      const int kb32 = kbase + hh * 32;

      // K frags (A layout), shared by both q-groups
      bf16x8 ak[4];
#pragma unroll
      for (int c = 0; c < 4; ++c) {
        const int ph = ((c << 1) | hi) ^ (ql & 7);
        ak[c] = *(const bf16x8*)(Kc + (hh * 32 + ql) * 128 + ph * 16);
      }

      // V frags (B layout), shared by both q-groups
      bf16x8 bv00, bv01, bv10, bv11;
      {
        const int p0 = ((hh << 2) | hi) ^ (ql & 7);
        const int p1 = ((hh << 2) | 2 | hi) ^ (ql & 7);
        bv00 = *(const bf16x8*)(Vc + ql * 128 + p0 * 16);
        bv01 = *(const bf16x8*)(Vc + (32 + ql) * 128 + p0 * 16);
        bv10 = *(const bf16x8*)(Vc + ql * 128 + p1 * 16);
        bv11 = *(const bf16x8*)(Vc + (32 + ql) * 128 + p1 * 16);
      }

#pragma unroll
      for (int G = 0; G < 2; ++G) {
        const int q0G = q0 + G * 32;
        const int qG = q0G + ql;

        // QK^T: S[k][q]
        f32x16 s = z16;
        __builtin_amdgcn_s_setprio(1);
#pragma unroll
        for (int c = 0; c < 4; ++c) s = MFMA32(ak[c], bq[G][c], s);
        __builtin_amdgcn_s_setprio(0);

        // bias in log2 domain (per-32 classification, same as R10)
        const bool farp = (kb32 >= q0G + 122);   // min rel >= 91
        const bool farn = (kb32 + 122 <= q0G);   // max rel <= -91
        if (farp || farn) {
          const float c = farp ? cpos : cneg;
#pragma unroll
          for (int r = 0; r < 16; ++r) s[r] = fmaf(s[r], LOG2E, c);
        } else {
          const int base = kb32 - qG + 186 + hi * 4;
#pragma unroll
          for (int r = 0; r < 16; ++r)
            s[r] = fmaf(s[r], LOG2E, Lb[base + (r & 3) + 8 * (r >> 2)]);
        }

        // tile max for my q (in-register + one cross-half exchange)
        float vm = s[0];
#pragma unroll
        for (int r = 1; r < 16; ++r) vm = fmaxf(vm, s[r]);
        vm = fmaxf(vm, __shfl_xor(vm, 32));

        // defer-max rescale (THR=8 in log2 domain; algebraically exact)
        if (__any(vm > m[G] + 8.0f)) {
          const float mn = fmaxf(m[G], vm);
          const float sc = fast_exp2(m[G] - mn);
          m[G] = mn;
          l[G] *= sc;
          sred[w][ql] = sc;
          __builtin_amdgcn_wave_barrier();
#pragma unroll
          for (int r = 0; r < 16; ++r) {
            const float sr = sred[w][(r & 3) + 8 * (r >> 2) + hi * 4];
            o[G][0][r] *= sr; o[G][1][r] *= sr;
          }
          __builtin_amdgcn_wave_barrier();
        }

        // P = exp2(s - m), row sum
        float p[16];
        float ls = 0.f;
#pragma unroll
        for (int r = 0; r < 16; ++r) { p[r] = fast_exp2(s[r] - m[G]); ls += p[r]; }
        l[G] += ls + __shfl_xor(ls, 32);

        // pack P -> PV A-frags (keys contiguous per lane via cross-half exchange)
        unsigned int wv[8], xv[8];
#pragma unroll
        for (int i = 0; i < 8; ++i) wv[i] = cvt_pk_bf16(p[2 * i], p[2 * i + 1]);
#pragma unroll
        for (int i = 0; i < 8; ++i) xv[i] = __shfl_xor(wv[i], 32);
        union { unsigned int u[4]; bf16x8 v; } pa0, pa1;
        pa0.u[0] = hi ? xv[2] : wv[0];
        pa0.u[1] = hi ? xv[3] : wv[1];
        pa0.u[2] = hi ? wv[2] : xv[0];
        pa0.u[3] = hi ? wv[3] : xv[1];
        pa1.u[0] = hi ? xv[6] : wv[4];
        pa1.u[1] = hi ? xv[7] : wv[5];
        pa1.u[2] = hi ? wv[6] : xv[4];
        pa1.u[3] = hi ? wv[7] : xv[5];

        // PV: O[q][d] += P[q][k] V[k][d]  (same accumulation order as R10)
        __builtin_amdgcn_s_setprio(1);
        o[G][0] = MFMA32(pa0.v, bv00, o[G][0]);
        o[G][0] = MFMA32(pa1.v, bv10, o[G][0]);
        o[G][1] = MFMA32(pa0.v, bv01, o[G][1]);
        o[G][1] = MFMA32(pa1.v, bv11, o[G][1]);
        __builtin_amdgcn_s_setprio(0);
      }
    }

    __syncthreads();
    cur ^= 1;
  }

  // finalize (per group; sred reuse separated by wave barriers)
#pragma unroll
  for (int G = 0; G < 2; ++G) {
    const float inv = 1.0f / l[G];
    __builtin_amdgcn_wave_barrier();
    sred[w][ql] = inv;
    __builtin_amdgcn_wave_barrier();
#pragma unroll
    for (int r = 0; r < 16; ++r) {
      const float ir = sred[w][(r & 3) + 8 * (r >> 2) + hi * 4];
      const int qq = q0 + G * 32 + (r & 3) + 8 * (r >> 2) + hi * 4;
      const size_t base = ((size_t)(b * 1024 + qq)) * 1024 + h * 64 + ql;
      ctx[base] = f2bf(o[G][0][r] * ir);
      ctx[base + 32] = f2bf(o[G][1][r] * ir);
    }
  }
}

// ---------------- output projection: out = ctx @ wo (f32 out) ----------------
__global__ __launch_bounds__(256) void k_gemm_out(
    const unsigned short* __restrict__ Cb, const unsigned short* __restrict__ Wot,
    float* __restrict__ out) {
  __shared__ alignas(16) unsigned short As[2 * 128 * 64];
  __shared__ alignas(16) unsigned short Bs[2 * 128 * 64];
  const int wid = (blockIdx.x & 7) * 64 + (blockIdx.x >> 3);  // XCD swizzle
  int tm = (wid >> 3) * 128, tn = (wid & 7) * 128;
  f32x4 acc[4][4];
  gemm_tile_lds(Cb, Wot, DMODEL, tm, tn, As, Bs, acc);

  const int lane = threadIdx.x & 63, w = threadIdx.x >> 6;
  const int wr = w >> 1, wc = w & 1, g = lane >> 4, t = lane & 15;
#pragma unroll
  for (int mi = 0; mi < 4; ++mi)
#pragma unroll
    for (int ni = 0; ni < 4; ++ni)
#pragma unroll
      for (int r = 0; r < 4; ++r) {
        int m = tm + wr * 64 + mi * 16 + g * 4 + r;
        int n = tn + wc * 64 + ni * 16 + t;
        out[(size_t)m * DMODEL + n] = acc[mi][ni][r];
      }
}

extern "C" void kernel_launch(void* const* d_in, const int* in_sizes, int n_in,
                              void* d_out, int out_size, void* d_ws, size_t ws_size,
                              hipStream_t stream) {
  const float* hs = (const float*)d_in[0];
  const float* wq = (const float*)d_in[1];
  const float* wk = (const float*)d_in[2];
  const float* wv = (const float*)d_in[3];
  const float* wo = (const float*)d_in[4];
  const float* rb = (const float*)d_in[5];

  char* ws = (char*)d_ws;
  unsigned short* Xb  = (unsigned short*)(ws + 0);          // 16 MB
  unsigned short* Wqt = (unsigned short*)(ws + 16777216);   // 2 MB
  unsigned short* Wkt = (unsigned short*)(ws + 18874368);
  unsigned short* Wvt = (unsigned short*)(ws + 20971520);
  unsigned short* Wot = (unsigned short*)(ws + 23068672);
  unsigned short* Qb  = (unsigned short*)(ws + 25165824);   // 16 MB
  unsigned short* Kb  = (unsigned short*)(ws + 41943040);   // 16 MB
  unsigned short* Vt  = (unsigned short*)(ws + 58720256);   // 16 MB
  unsigned short* Cb  = (unsigned short*)(ws + 75497472);   // 16 MB
  float* bt           = (float*)(ws + 92274688);            // 128 KB

  k_convert_x<<<4096, 256, 0, stream>>>(hs, Xb, NROWS * DMODEL);
  k_transpose_w<<<dim3(1024, 1, 4), 256, 0, stream>>>(wq, wk, wv, wo, Wqt, Wkt, Wvt, Wot);
  k_bias_table<<<128, 256, 0, stream>>>(rb, bt);
  k_gemm_qkv<<<dim3(512, 1, 3), 256, 0, stream>>>(Xb, Wqt, Wkt, Wvt, Qb, Kb, Vt);
  k_attn<<<512, 256, 0, stream>>>(Qb, Kb, Vt, bt, Cb);
  k_gemm_out<<<512, 256, 0, stream>>>(Cb, Wot, (float*)d_out);
}

// Round 13
// 168.769 us; speedup vs baseline: 1.1989x; 1.1989x over previous
//
#include <hip/hip_runtime.h>
#include <stdint.h>

typedef __attribute__((ext_vector_type(8))) short bf16x8;
typedef __attribute__((ext_vector_type(4))) float f32x4;
typedef __attribute__((ext_vector_type(16))) float f32x16;
typedef __attribute__((ext_vector_type(8))) unsigned short ushort8;
typedef __attribute__((ext_vector_type(4))) unsigned short ushort4v;

#define MFMA16(a, b, c) __builtin_amdgcn_mfma_f32_16x16x32_bf16((a), (b), (c), 0, 0, 0)
#define MFMA32(a, b, c) __builtin_amdgcn_mfma_f32_32x32x16_bf16((a), (b), (c), 0, 0, 0)

// B=8, S=1024, D=1024, H=16, DK=64
#define SLEN 1024
#define NHEAD 16
#define HDIM 64
#define DMODEL 1024
#define NROWS 8192  // B*S
#define LOG2E 1.44269504088896340736f

__device__ __forceinline__ unsigned short f2bf(float f) {
  unsigned int u = __float_as_uint(f);
  u += 0x7FFFu + ((u >> 16) & 1u);   // RNE
  return (unsigned short)(u >> 16);
}

__device__ __forceinline__ float fast_exp2(float x) {
#if __has_builtin(__builtin_amdgcn_exp2f)
  return __builtin_amdgcn_exp2f(x);
#else
  float r; asm("v_exp_f32 %0, %1" : "=v"(r) : "v"(x)); return r;
#endif
}

__device__ __forceinline__ unsigned int cvt_pk_bf16(float lo, float hi) {
  unsigned int r;
  asm("v_cvt_pk_bf16_f32 %0, %1, %2" : "=v"(r) : "v"(lo), "v"(hi));
  return r;
}

// async global->LDS, 16B per lane; LDS dest = wave-uniform base + lane*16 (HW).
__device__ __forceinline__ void gload_lds16(const void* g, void* l) {
  __builtin_amdgcn_global_load_lds(
      (const __attribute__((address_space(1))) void*)g,
      (__attribute__((address_space(3))) void*)l, 16, 0, 0);
}

// ---------------- fused prep: convert X, transpose weights, bias table ----------------
// grid 8320 x 256: [0,4096) convert_x, [4096,8192) transpose (z = (i-4096)>>10),
// [8192,8320) bias table.
__global__ __launch_bounds__(256) void k_prep(
    const float* __restrict__ x, unsigned short* __restrict__ xb,
    const float* __restrict__ w0, const float* __restrict__ w1,
    const float* __restrict__ w2, const float* __restrict__ w3,
    unsigned short* __restrict__ o0, unsigned short* __restrict__ o1,
    unsigned short* __restrict__ o2, unsigned short* __restrict__ o3,
    const float* __restrict__ rel_bias, float* __restrict__ bt) {
  const int bi = blockIdx.x;
  const int tid = threadIdx.x;
  if (bi < 4096) {
    // convert hidden_states f32 -> bf16 (8 elems/thread)
    int idx = (bi * 256 + tid) * 8;
    float4 a = *(const float4*)(x + idx);
    float4 b = *(const float4*)(x + idx + 4);
    ushort8 o;
    o[0] = f2bf(a.x); o[1] = f2bf(a.y); o[2] = f2bf(a.z); o[3] = f2bf(a.w);
    o[4] = f2bf(b.x); o[5] = f2bf(b.y); o[6] = f2bf(b.z); o[7] = f2bf(b.w);
    *(ushort8*)(xb + idx) = o;
  } else if (bi < 8192) {
    // transpose + convert W[K][N] f32 -> Wt[N][K] bf16
    const int t = bi - 4096;
    const int z = t >> 10;
    const float* w = (z == 0) ? w0 : (z == 1) ? w1 : (z == 2) ? w2 : w3;
    unsigned short* o = (z == 0) ? o0 : (z == 1) ? o1 : (z == 2) ? o2 : o3;
    __shared__ unsigned short tile[32][33];
    const int bx = t & 31, by = (t & 1023) >> 5;
#pragma unroll
    for (int p = 0; p < 4; ++p) {
      int idx = tid + p * 256;
      int r = idx >> 5, c = idx & 31;
      tile[r][c] = f2bf(w[(size_t)(by * 32 + r) * DMODEL + bx * 32 + c]);
    }
    __syncthreads();
#pragma unroll
    for (int p = 0; p < 4; ++p) {
      int idx = tid + p * 256;
      int r = idx >> 5, c = idx & 31;
      o[(size_t)(bx * 32 + r) * DMODEL + by * 32 + c] = tile[c][r];
    }
  } else {
    // bias table: bt[h][rel+1023] * log2e, rel = k-q
    int i = (bi - 8192) * 256 + tid;
    if (i >= NHEAD * 2047) return;
    int h = i / 2047, rdx = i % 2047;
    int rel = rdx - 1023;
    int rb = (rel > 0) ? 16 : 0;
    int rp = (rel < 0) ? -rel : rel;
    int bucket;
    if (rp < 8) {
      bucket = rb + rp;
    } else {
      int large;
      if (rp >= 91) {
        large = 15;
      } else {
        int nb = 31 - __clz(rp);
        long long sq = (long long)rp * rp;
        int f2 = 2 * nb + ((sq >= (1LL << (2 * nb + 1))) ? 1 : 0);
        large = 8 + (f2 - 6);
        if (large > 15) large = 15;
      }
      bucket = rb + large;
    }
    bt[h * 2048 + rdx] = rel_bias[bucket * 16 + h] * LOG2E;
  }
}

// ---------------- 2-phase GEMM core, BK=64, XOR-swizzled LDS (R10-verified) ----------------
__device__ __forceinline__ void gemm_tile_lds(const unsigned short* __restrict__ A,
                                              const unsigned short* __restrict__ Bt,
                                              int K, int tm, int tn,
                                              unsigned short* As, unsigned short* Bs,
                                              f32x4 acc[4][4]) {
  const int tid = threadIdx.x;
  const int lane = tid & 63;
  const int w = tid >> 6;
  const int wr = w >> 1, wc = w & 1;
  const int g = lane >> 4, t = lane & 15;
  const int NKT = K >> 6;   // BK=64

  auto stageT = [&](int bufo, int ko) {
#pragma unroll
    for (int j = 0; j < 4; ++j) {
      const int r = w * 32 + j * 8 + (lane >> 3);
      const int lc = (lane & 7) ^ (r & 7);
      gload_lds16(A + (size_t)(tm + r) * K + ko + lc * 8, As + bufo + (w * 4 + j) * 512);
      gload_lds16(Bt + (size_t)(tn + r) * K + ko + lc * 8, Bs + bufo + (w * 4 + j) * 512);
    }
  };

  f32x4 z = {0.f, 0.f, 0.f, 0.f};
#pragma unroll
  for (int mi = 0; mi < 4; ++mi)
#pragma unroll
    for (int ni = 0; ni < 4; ++ni) acc[mi][ni] = z;

  stageT(0, 0);
  __syncthreads();

#pragma unroll 1
  for (int kt = 0; kt < NKT; ++kt) {
    const int cur = (kt & 1) * 8192;
    if (kt + 1 < NKT) stageT(cur ^ 8192, (kt + 1) * 64);

    bf16x8 af[2][4], bfr[2][4];
#pragma unroll
    for (int kk = 0; kk < 2; ++kk)
#pragma unroll
      for (int mi = 0; mi < 4; ++mi) {
        const int ra = wr * 64 + mi * 16 + t;
        const int pa = ((kk << 2) | g) ^ (ra & 7);
        af[kk][mi] = *(const bf16x8*)&As[cur + ra * 64 + pa * 8];
      }
#pragma unroll
    for (int kk = 0; kk < 2; ++kk)
#pragma unroll
      for (int ni = 0; ni < 4; ++ni) {
        const int rb = wc * 64 + ni * 16 + t;
        const int pb = ((kk << 2) | g) ^ (rb & 7);
        bfr[kk][ni] = *(const bf16x8*)&Bs[cur + rb * 64 + pb * 8];
      }
#pragma unroll
    for (int kk = 0; kk < 2; ++kk)
#pragma unroll
      for (int mi = 0; mi < 4; ++mi)
#pragma unroll
        for (int ni = 0; ni < 4; ++ni)
          acc[mi][ni] = MFMA16(af[kk][mi], bfr[kk][ni], acc[mi][ni]);

    __syncthreads();
  }
}

// ---------------- QKV projection ----------------
__global__ __launch_bounds__(256) void k_gemm_qkv(
    const unsigned short* __restrict__ Xb,
    const unsigned short* __restrict__ Wqt, const unsigned short* __restrict__ Wkt,
    const unsigned short* __restrict__ Wvt,
    unsigned short* __restrict__ Qb, unsigned short* __restrict__ Kb,
    unsigned short* __restrict__ Vt) {
  __shared__ alignas(16) unsigned short As[2 * 128 * 64];
  __shared__ alignas(16) unsigned short Bs[2 * 128 * 64];
  int z = blockIdx.z;
  const unsigned short* Bt = (z == 0) ? Wqt : (z == 1) ? Wkt : Wvt;
  const int wid = (blockIdx.x & 7) * 64 + (blockIdx.x >> 3);
  int tm = (wid >> 3) * 128, tn = (wid & 7) * 128;
  f32x4 acc[4][4];
  gemm_tile_lds(Xb, Bt, DMODEL, tm, tn, As, Bs, acc);

  const int lane = threadIdx.x & 63, w = threadIdx.x >> 6;
  const int wr = w >> 1, wc = w & 1, g = lane >> 4, t = lane & 15;
  if (z < 2) {
    unsigned short* O = (z == 0) ? Qb : Kb;
#pragma unroll
    for (int mi = 0; mi < 4; ++mi)
#pragma unroll
      for (int ni = 0; ni < 4; ++ni)
#pragma unroll
        for (int r = 0; r < 4; ++r) {
          int m = tm + wr * 64 + mi * 16 + g * 4 + r;
          int n = tn + wc * 64 + ni * 16 + t;
          int b = m >> 10, s = m & 1023, h = n >> 6, d = n & 63;
          O[((size_t)((b * 16 + h) * 1024 + s)) * 64 + d] = f2bf(acc[mi][ni][r]);
        }
  } else {
#pragma unroll
    for (int mi = 0; mi < 4; ++mi)
#pragma unroll
      for (int ni = 0; ni < 4; ++ni) {
        int m0 = tm + wr * 64 + mi * 16 + g * 4;
        int n = tn + wc * 64 + ni * 16 + t;
        int b = m0 >> 10, s0 = m0 & 1023, h = n >> 6, d = n & 63;
        ushort4v pk;
#pragma unroll
        for (int r = 0; r < 4; ++r) pk[r] = f2bf(acc[mi][ni][r]);
        *(ushort4v*)&Vt[((size_t)((b * 16 + h) * 64 + d) * 1024) + s0] = pk;
      }
  }
}

// ---------------- flash attention (R10-verified structure; max via balanced tree) ----------------
// grid 512 (XCD-swizzled); block 512 = 8 waves; wave = 32 q-rows (256 q-rows/block).
__global__ __launch_bounds__(512) void k_attn(
    const unsigned short* __restrict__ Qb, const unsigned short* __restrict__ Kb,
    const unsigned short* __restrict__ Vt, const float* __restrict__ bt,
    unsigned short* __restrict__ ctx) {
  __shared__ alignas(16) unsigned short Ks[2][64 * 64];  // [key][d] swizzled, 8KB each
  __shared__ alignas(16) unsigned short Vs[2][64 * 64];  // [d][key] swizzled, 8KB each
  __shared__ alignas(16) float Lb[376];                  // bias, rel in [-186,189], log2e domain
  __shared__ float sred[8][32];

  const int wid = ((blockIdx.x & 7) << 6) | (blockIdx.x >> 3);  // XCD-local head grouping
  const int bh = wid >> 2, qb = wid & 3;
  const int h = bh & 15, b = bh >> 4;
  const int tid = threadIdx.x;
  const int lane = tid & 63, w = tid >> 6;
  const int ql = lane & 31, hi = lane >> 5;
  const int q0 = qb * 256 + w * 32;
  const int q = q0 + ql;

  for (int i = tid; i < 376; i += 512) Lb[i] = bt[(size_t)h * 2048 + 837 + i];  // 837 = 1023-186

  const unsigned short* Qp = Qb + (size_t)bh * SLEN * 64;
  const unsigned short* Kp = Kb + (size_t)bh * SLEN * 64;
  const unsigned short* Vp = Vt + (size_t)bh * 64 * SLEN;

  bf16x8 bq[4];
#pragma unroll
  for (int c = 0; c < 4; ++c)
    bq[c] = *(const bf16x8*)(Qp + (size_t)q * 64 + c * 16 + hi * 8);

  const f32x16 z16 = {0.f,0.f,0.f,0.f,0.f,0.f,0.f,0.f,0.f,0.f,0.f,0.f,0.f,0.f,0.f,0.f};
  f32x16 o0 = z16, o1 = z16;
  float m = -INFINITY, l = 0.f;

  auto stage = [&](int buf, int kbase) {
    int lb = w * 1024 + lane * 16;
    int row = lb >> 7;
    int lc = ((lb >> 4) & 7) ^ (row & 7);
    gload_lds16(Kp + (size_t)(kbase + row) * 64 + lc * 8, &Ks[buf][w * 512]);
    gload_lds16(Vp + (size_t)row * SLEN + kbase + lc * 8, &Vs[buf][w * 512]);
  };

  stage(0, 0);
  __syncthreads();
  const float cpos = Lb[186 + 91], cneg = Lb[186 - 91];

  int cur = 0;
#pragma unroll 1
  for (int kt = 0; kt < 16; ++kt) {
    const int kbase = kt * 64;
    if (kt != 15) stage(cur ^ 1, kbase + 64);

    const char* Kc = (const char*)Ks[cur];
    const char* Vc = (const char*)Vs[cur];

#pragma unroll
    for (int hh = 0; hh < 2; ++hh) {
      const int kb32 = kbase + hh * 32;

      bf16x8 ak[4];
#pragma unroll
      for (int c = 0; c < 4; ++c) {
        const int ph = ((c << 1) | hi) ^ (ql & 7);
        ak[c] = *(const bf16x8*)(Kc + (hh * 32 + ql) * 128 + ph * 16);
      }

      bf16x8 bv00, bv01, bv10, bv11;
      {
        const int p0 = ((hh << 2) | hi) ^ (ql & 7);
        const int p1 = ((hh << 2) | 2 | hi) ^ (ql & 7);
        bv00 = *(const bf16x8*)(Vc + ql * 128 + p0 * 16);
        bv01 = *(const bf16x8*)(Vc + (32 + ql) * 128 + p0 * 16);
        bv10 = *(const bf16x8*)(Vc + ql * 128 + p1 * 16);
        bv11 = *(const bf16x8*)(Vc + (32 + ql) * 128 + p1 * 16);
      }

      // QK^T: S[k][q]
      f32x16 s = z16;
      __builtin_amdgcn_s_setprio(1);
#pragma unroll
      for (int c = 0; c < 4; ++c) s = MFMA32(ak[c], bq[c], s);
      __builtin_amdgcn_s_setprio(0);

      // bias in log2 domain
      const bool farp = (kb32 >= q0 + 122);
      const bool farn = (kb32 + 122 <= q0);
      if (farp || farn) {
        const float c = farp ? cpos : cneg;
#pragma unroll
        for (int r = 0; r < 16; ++r) s[r] = fmaf(s[r], LOG2E, c);
      } else {
        const int base = kb32 - q + 186 + hi * 4;
#pragma unroll
        for (int r = 0; r < 16; ++r)
          s[r] = fmaf(s[r], LOG2E, Lb[base + (r & 3) + 8 * (r >> 2)]);
      }

      // tile max: balanced tree (fmax exact -> bit-identical) + one cross-half exchange
      float t0 = fmaxf(fmaxf(s[0], s[1]), fmaxf(s[2], s[3]));
      float t1 = fmaxf(fmaxf(s[4], s[5]), fmaxf(s[6], s[7]));
      float t2 = fmaxf(fmaxf(s[8], s[9]), fmaxf(s[10], s[11]));
      float t3 = fmaxf(fmaxf(s[12], s[13]), fmaxf(s[14], s[15]));
      float vm = fmaxf(fmaxf(t0, t1), fmaxf(t2, t3));
      vm = fmaxf(vm, __shfl_xor(vm, 32));

      // defer-max rescale (THR=8 in log2 domain; algebraically exact)
      if (__any(vm > m + 8.0f)) {
        const float mn = fmaxf(m, vm);
        const float sc = fast_exp2(m - mn);
        m = mn;
        l *= sc;
        sred[w][ql] = sc;
        __builtin_amdgcn_wave_barrier();
#pragma unroll
        for (int r = 0; r < 16; ++r) {
          const float sr = sred[w][(r & 3) + 8 * (r >> 2) + hi * 4];
          o0[r] *= sr; o1[r] *= sr;
        }
        __builtin_amdgcn_wave_barrier();
      }

      // P = exp2(s - m), row sum (serial order preserved — float add not reassociated)
      float p[16];
      float ls = 0.f;
#pragma unroll
      for (int r = 0; r < 16; ++r) { p[r] = fast_exp2(s[r] - m); ls += p[r]; }
      l += ls + __shfl_xor(ls, 32);

      // pack P -> PV A-frags (keys contiguous per lane via cross-half exchange)
      unsigned int wv[8], xv[8];
#pragma unroll
      for (int i = 0; i < 8; ++i) wv[i] = cvt_pk_bf16(p[2 * i], p[2 * i + 1]);
#pragma unroll
      for (int i = 0; i < 8; ++i) xv[i] = __shfl_xor(wv[i], 32);
      union { unsigned int u[4]; bf16x8 v; } pa0, pa1;
      pa0.u[0] = hi ? xv[2] : wv[0];
      pa0.u[1] = hi ? xv[3] : wv[1];
      pa0.u[2] = hi ? wv[2] : xv[0];
      pa0.u[3] = hi ? wv[3] : xv[1];
      pa1.u[0] = hi ? xv[6] : wv[4];
      pa1.u[1] = hi ? xv[7] : wv[5];
      pa1.u[2] = hi ? wv[6] : xv[4];
      pa1.u[3] = hi ? wv[7] : xv[5];

      // PV: O[q][d] += P[q][k] V[k][d]
      __builtin_amdgcn_s_setprio(1);
      o0 = MFMA32(pa0.v, bv00, o0);
      o0 = MFMA32(pa1.v, bv10, o0);
      o1 = MFMA32(pa0.v, bv01, o1);
      o1 = MFMA32(pa1.v, bv11, o1);
      __builtin_amdgcn_s_setprio(0);
    }

    __syncthreads();
    cur ^= 1;
  }

  // finalize
  const float inv = 1.0f / l;
  sred[w][ql] = inv;
  __builtin_amdgcn_wave_barrier();
#pragma unroll
  for (int r = 0; r < 16; ++r) {
    const float ir = sred[w][(r & 3) + 8 * (r >> 2) + hi * 4];
    const int qq = q0 + (r & 3) + 8 * (r >> 2) + hi * 4;
    const size_t base = ((size_t)(b * 1024 + qq)) * 1024 + h * 64 + ql;
    ctx[base] = f2bf(o0[r] * ir);
    ctx[base + 32] = f2bf(o1[r] * ir);
  }
}

// ---------------- output projection: out = ctx @ wo (f32 out) ----------------
__global__ __launch_bounds__(256) void k_gemm_out(
    const unsigned short* __restrict__ Cb, const unsigned short* __restrict__ Wot,
    float* __restrict__ out) {
  __shared__ alignas(16) unsigned short As[2 * 128 * 64];
  __shared__ alignas(16) unsigned short Bs[2 * 128 * 64];
  const int wid = (blockIdx.x & 7) * 64 + (blockIdx.x >> 3);  // XCD swizzle
  int tm = (wid >> 3) * 128, tn = (wid & 7) * 128;
  f32x4 acc[4][4];
  gemm_tile_lds(Cb, Wot, DMODEL, tm, tn, As, Bs, acc);

  const int lane = threadIdx.x & 63, w = threadIdx.x >> 6;
  const int wr = w >> 1, wc = w & 1, g = lane >> 4, t = lane & 15;
#pragma unroll
  for (int mi = 0; mi < 4; ++mi)
#pragma unroll
    for (int ni = 0; ni < 4; ++ni)
#pragma unroll
      for (int r = 0; r < 4; ++r) {
        int m = tm + wr * 64 + mi * 16 + g * 4 + r;
        int n = tn + wc * 64 + ni * 16 + t;
        out[(size_t)m * DMODEL + n] = acc[mi][ni][r];
      }
}

extern "C" void kernel_launch(void* const* d_in, const int* in_sizes, int n_in,
                              void* d_out, int out_size, void* d_ws, size_t ws_size,
                              hipStream_t stream) {
  const float* hs = (const float*)d_in[0];
  const float* wq = (const float*)d_in[1];
  const float* wk = (const float*)d_in[2];
  const float* wv = (const float*)d_in[3];
  const float* wo = (const float*)d_in[4];
  const float* rb = (const float*)d_in[5];

  char* ws = (char*)d_ws;
  unsigned short* Xb  = (unsigned short*)(ws + 0);          // 16 MB
  unsigned short* Wqt = (unsigned short*)(ws + 16777216);   // 2 MB
  unsigned short* Wkt = (unsigned short*)(ws + 18874368);
  unsigned short* Wvt = (unsigned short*)(ws + 20971520);
  unsigned short* Wot = (unsigned short*)(ws + 23068672);
  unsigned short* Qb  = (unsigned short*)(ws + 25165824);   // 16 MB
  unsigned short* Kb  = (unsigned short*)(ws + 41943040);   // 16 MB
  unsigned short* Vt  = (unsigned short*)(ws + 58720256);   // 16 MB
  unsigned short* Cb  = (unsigned short*)(ws + 75497472);   // 16 MB
  float* bt           = (float*)(ws + 92274688);            // 128 KB

  k_prep<<<8320, 256, 0, stream>>>(hs, Xb, wq, wk, wv, wo, Wqt, Wkt, Wvt, Wot, rb, bt);
  k_gemm_qkv<<<dim3(512, 1, 3), 256, 0, stream>>>(Xb, Wqt, Wkt, Wvt, Qb, Kb, Vt);
  k_attn<<<512, 512, 0, stream>>>(Qb, Kb, Vt, bt, Cb);
  k_gemm_out<<<512, 256, 0, stream>>>(Cb, Wot, (float*)d_out);
}